// Round 1
// baseline (1824.726 us; speedup 1.0000x reference)
//
#include <hip/hip_runtime.h>
#include <stdint.h>

#define HIDDEN 256
#define NMOLS 5000
#define APM 30
#define NATOMS 150000
#define NBONDS 320000
#define MAXNB 6
#define AFD 133
#define BFD 147
#define A1 (NATOMS + 1)
#define B1 (NBONDS + 1)
#define KI 160   // padded bond-feature K (147 -> 160)
#define KO 416   // padded readout K (133 f_atoms + 27 pad + 256 amsg)

typedef __bf16 bfx8 __attribute__((ext_vector_type(8)));
typedef float fx4 __attribute__((ext_vector_type(4)));
typedef unsigned short u16x8 __attribute__((ext_vector_type(8)));

__device__ __forceinline__ float b2f(unsigned short u) {
    union { unsigned int i; float f; } v; v.i = ((unsigned int)u) << 16; return v.f;
}
__device__ __forceinline__ unsigned short f2b(float f) {
    union { float f; unsigned int i; } v; v.f = f;
    unsigned int r = v.i + 0x7FFFu + ((v.i >> 16) & 1u);
    return (unsigned short)(r >> 16);
}

// ---------------- weight conversion / padding ----------------
__global__ void k_convw(const float* __restrict__ Wi, const float* __restrict__ Wh,
                        const float* __restrict__ Wo,
                        unsigned short* __restrict__ wi, unsigned short* __restrict__ wh,
                        unsigned short* __restrict__ wo) {
    int t = blockIdx.x * 256 + threadIdx.x;
    if (t < 256 * KI) {
        int n = t / KI, k = t % KI;
        wi[t] = (k < BFD) ? f2b(Wi[n * BFD + k]) : (unsigned short)0;
        return;
    }
    int t2 = t - 256 * KI;
    if (t2 < 256 * 256) {
        wh[t2] = f2b(Wh[t2]);
        return;
    }
    int t3 = t2 - 256 * 256;
    if (t3 < 256 * KO) {
        int n = t3 / KO, k = t3 % KO;
        float v = 0.f;
        if (k < AFD) v = Wo[n * (AFD + HIDDEN) + k];
        else if (k >= 160) v = Wo[n * (AFD + HIDDEN) + AFD + (k - 160)];
        wo[t3] = f2b(v);
    }
}

// ---------------- K1: inp = f_bonds @ Wi^T ; msg = relu(inp) ----------------
__global__ __launch_bounds__(256) void k_gemm_wi(
    const float* __restrict__ fb, const unsigned short* __restrict__ wi,
    unsigned short* __restrict__ inp, unsigned short* __restrict__ msg)
{
    __shared__ unsigned short lds[64 * KI];  // row stride 320 B (conflict-floor naturally)
    const int m0 = blockIdx.x * 64;
    const int tid = threadIdx.x;
    {
        const int r = tid >> 2, p = tid & 3;
        const int b = m0 + r;
        const bool ok = (b < B1);
        const float* src = fb + (size_t)b * BFD;
        unsigned short* drow = lds + r * KI;
#pragma unroll
        for (int i = 0; i < 5; ++i) {
            const int c0 = (i * 4 + p) * 8;
            u16x8 o;
#pragma unroll
            for (int e = 0; e < 8; ++e) {
                float v = (ok && (c0 + e) < BFD) ? src[c0 + e] : 0.f;
                o[e] = f2b(v);
            }
            *(u16x8*)(drow + c0) = o;
        }
    }
    __syncthreads();

    const int wv = tid >> 6, ln = tid & 63;
    const int l15 = ln & 15, lhi = ln >> 4;
    fx4 acc[4][4];
#pragma unroll
    for (int a = 0; a < 4; ++a)
#pragma unroll
        for (int b = 0; b < 4; ++b)
#pragma unroll
            for (int q = 0; q < 4; ++q) acc[a][b][q] = 0.f;

#pragma unroll
    for (int ks = 0; ks < 5; ++ks) {
        const int kk = ks * 32 + lhi * 8;
        bfx8 af[4], bb[4];
#pragma unroll
        for (int mf = 0; mf < 4; ++mf) {
            const int rr = mf * 16 + l15;
            af[mf] = *(const bfx8*)(lds + rr * KI + kk);
        }
#pragma unroll
        for (int nf = 0; nf < 4; ++nf) {
            const int n = wv * 64 + nf * 16 + l15;
            bb[nf] = *(const bfx8*)(wi + n * KI + kk);
        }
#pragma unroll
        for (int mf = 0; mf < 4; ++mf)
#pragma unroll
            for (int nf = 0; nf < 4; ++nf)
                acc[mf][nf] = __builtin_amdgcn_mfma_f32_16x16x32_bf16(af[mf], bb[nf], acc[mf][nf], 0, 0, 0);
    }
    const int cb = wv * 64 + l15;
    const int rb = lhi * 4;
#pragma unroll
    for (int mf = 0; mf < 4; ++mf) {
#pragma unroll
        for (int j = 0; j < 4; ++j) {
            const int g = m0 + mf * 16 + rb + j;
            if (g < B1) {
#pragma unroll
                for (int nf = 0; nf < 4; ++nf) {
                    const size_t idx = (size_t)g * HIDDEN + cb + nf * 16;
                    const float v = acc[mf][nf][j];
                    inp[idx] = f2b(v);
                    msg[idx] = f2b(v > 0.f ? v : 0.f);
                }
            }
        }
    }
}

// ---------------- K2: amsg[a] = sum_j msg[a2b[a][j]] ----------------
__global__ __launch_bounds__(256) void k_gather(
    const unsigned short* __restrict__ msg, const int* __restrict__ a2b,
    unsigned short* __restrict__ amsg)
{
    const int gt = blockIdx.x * 256 + threadIdx.x;
    const int atom = gt >> 5;
    const int s = gt & 31;
    if (atom >= A1) return;
    const int* nb = a2b + atom * MAXNB;
    float acc[8];
#pragma unroll
    for (int e = 0; e < 8; ++e) acc[e] = 0.f;
#pragma unroll
    for (int j = 0; j < MAXNB; ++j) {
        const int b = nb[j];
        u16x8 v = *(const u16x8*)(msg + (size_t)b * HIDDEN + s * 8);
#pragma unroll
        for (int e = 0; e < 8; ++e) acc[e] += b2f(v[e]);
    }
    u16x8 o;
#pragma unroll
    for (int e = 0; e < 8; ++e) o[e] = f2b(acc[e]);
    *(u16x8*)(amsg + (size_t)atom * HIDDEN + s * 8) = o;
}

// ---------------- K3: msgn = relu(inp + (amsg[b2a]-msgp[b2revb]) @ Wh^T) ----------------
__global__ __launch_bounds__(256) void k_gemm_wh(
    const unsigned short* __restrict__ amsg,
    const unsigned short* __restrict__ msgp,
    const int* __restrict__ b2a, const int* __restrict__ b2revb,
    const unsigned short* __restrict__ wh,
    const unsigned short* __restrict__ inp,
    unsigned short* __restrict__ msgn)
{
    __shared__ unsigned short lds[64 * 256];  // 512 B rows, XOR-swizzled
    const int m0 = blockIdx.x * 64;
    const int tid = threadIdx.x;
    {
        const int r = tid >> 2, p = tid & 3;
        const int b = m0 + r;
        const bool ok = (b < B1);
        int i1 = 0, i2 = 0;
        if (ok) { i1 = b2a[b]; i2 = b2revb[b]; }
        const unsigned short* s1 = amsg + (size_t)i1 * HIDDEN;
        const unsigned short* s2 = msgp + (size_t)i2 * HIDDEN;
        char* ldsrow = (char*)lds + r * 512;
        const int sw = (r & 7) << 4;
#pragma unroll
        for (int i = 0; i < 8; ++i) {
            const int slot = i * 4 + p;
            const int c0 = slot * 8;
            u16x8 o;
            if (ok) {
                u16x8 a = *(const u16x8*)(s1 + c0);
                u16x8 m = *(const u16x8*)(s2 + c0);
#pragma unroll
                for (int e = 0; e < 8; ++e) o[e] = f2b(b2f(a[e]) - b2f(m[e]));
            } else {
#pragma unroll
                for (int e = 0; e < 8; ++e) o[e] = 0;
            }
            *(u16x8*)(ldsrow + ((slot * 16) ^ sw)) = o;
        }
    }
    __syncthreads();

    const int wv = tid >> 6, ln = tid & 63;
    const int l15 = ln & 15, lhi = ln >> 4;
    fx4 acc[4][4];
#pragma unroll
    for (int a = 0; a < 4; ++a)
#pragma unroll
        for (int b = 0; b < 4; ++b)
#pragma unroll
            for (int q = 0; q < 4; ++q) acc[a][b][q] = 0.f;

#pragma unroll
    for (int ks = 0; ks < 8; ++ks) {
        const int kk = ks * 32 + lhi * 8;
        bfx8 af[4], bb[4];
#pragma unroll
        for (int mf = 0; mf < 4; ++mf) {
            const int rr = mf * 16 + l15;
            af[mf] = *(const bfx8*)((const char*)lds + rr * 512 + ((kk * 2) ^ ((rr & 7) << 4)));
        }
#pragma unroll
        for (int nf = 0; nf < 4; ++nf) {
            const int n = wv * 64 + nf * 16 + l15;
            bb[nf] = *(const bfx8*)(wh + n * 256 + kk);
        }
#pragma unroll
        for (int mf = 0; mf < 4; ++mf)
#pragma unroll
            for (int nf = 0; nf < 4; ++nf)
                acc[mf][nf] = __builtin_amdgcn_mfma_f32_16x16x32_bf16(af[mf], bb[nf], acc[mf][nf], 0, 0, 0);
    }
    const int cb = wv * 64 + l15;
    const int rb = lhi * 4;
#pragma unroll
    for (int mf = 0; mf < 4; ++mf) {
#pragma unroll
        for (int j = 0; j < 4; ++j) {
            const int g = m0 + mf * 16 + rb + j;
            if (g < B1) {
#pragma unroll
                for (int nf = 0; nf < 4; ++nf) {
                    const size_t idx = (size_t)g * HIDDEN + cb + nf * 16;
                    float v = b2f(inp[idx]) + acc[mf][nf][j];
                    msgn[idx] = f2b(v > 0.f ? v : 0.f);
                }
            }
        }
    }
}

// ---------------- K4: atom_hiddens = relu(concat(f_atoms, amsg) @ Wo^T + bo) ----------------
__global__ __launch_bounds__(256) void k_gemm_wo(
    const float* __restrict__ fa,
    const unsigned short* __restrict__ amsg,
    const unsigned short* __restrict__ wo,
    const float* __restrict__ bo,
    float* __restrict__ ah)
{
    __shared__ unsigned short lds[64 * KO];  // 53248 B, 832 B rows (conflict-floor)
    const int m0 = blockIdx.x * 64;
    const int tid = threadIdx.x;
    {
        const int r = tid >> 2, p = tid & 3;
        const int a = m0 + r;
        const bool ok = (a < A1);
        const float* src = fa + (size_t)a * AFD;
        unsigned short* drow = lds + r * KO;
#pragma unroll
        for (int i = 0; i < 13; ++i) {
            const int c0 = (i * 4 + p) * 8;
            u16x8 o;
            if (ok && c0 + 8 <= AFD) {
#pragma unroll
                for (int e = 0; e < 8; ++e) o[e] = f2b(src[c0 + e]);
            } else if (ok && c0 < AFD) {
#pragma unroll
                for (int e = 0; e < 8; ++e) o[e] = (c0 + e < AFD) ? f2b(src[c0 + e]) : (unsigned short)0;
            } else if (ok && c0 >= 160) {
                o = *(const u16x8*)(amsg + (size_t)a * HIDDEN + (c0 - 160));
            } else {
#pragma unroll
                for (int e = 0; e < 8; ++e) o[e] = 0;
            }
            *(u16x8*)(drow + c0) = o;
        }
    }
    __syncthreads();

    const int wv = tid >> 6, ln = tid & 63;
    const int l15 = ln & 15, lhi = ln >> 4;
    fx4 acc[4][4];
#pragma unroll
    for (int a = 0; a < 4; ++a)
#pragma unroll
        for (int b = 0; b < 4; ++b)
#pragma unroll
            for (int q = 0; q < 4; ++q) acc[a][b][q] = 0.f;

#pragma unroll
    for (int ks = 0; ks < 13; ++ks) {
        const int kk = ks * 32 + lhi * 8;
        bfx8 af[4], bb[4];
#pragma unroll
        for (int mf = 0; mf < 4; ++mf) {
            const int rr = mf * 16 + l15;
            af[mf] = *(const bfx8*)(lds + rr * KO + kk);
        }
#pragma unroll
        for (int nf = 0; nf < 4; ++nf) {
            const int n = wv * 64 + nf * 16 + l15;
            bb[nf] = *(const bfx8*)(wo + n * KO + kk);
        }
#pragma unroll
        for (int mf = 0; mf < 4; ++mf)
#pragma unroll
            for (int nf = 0; nf < 4; ++nf)
                acc[mf][nf] = __builtin_amdgcn_mfma_f32_16x16x32_bf16(af[mf], bb[nf], acc[mf][nf], 0, 0, 0);
    }
    const int cb = wv * 64 + l15;
    const int rb = lhi * 4;
    float bias[4];
#pragma unroll
    for (int nf = 0; nf < 4; ++nf) bias[nf] = bo[cb + nf * 16];
#pragma unroll
    for (int mf = 0; mf < 4; ++mf) {
#pragma unroll
        for (int j = 0; j < 4; ++j) {
            const int g = m0 + mf * 16 + rb + j;
            if (g < A1) {
#pragma unroll
                for (int nf = 0; nf < 4; ++nf) {
                    float v = acc[mf][nf][j] + bias[nf];
                    ah[(size_t)g * HIDDEN + cb + nf * 16] = (v > 0.f ? v : 0.f);
                }
            }
        }
    }
}

// ---------------- K5: per-molecule mean over 30 atoms ----------------
__global__ __launch_bounds__(256) void k_pool(const float* __restrict__ ah, float* __restrict__ out) {
    const int mol = blockIdx.x;
    const int h = threadIdx.x;
    const float* base = ah + ((size_t)(1 + mol * APM)) * HIDDEN + h;
    float s = 0.f;
#pragma unroll
    for (int i = 0; i < APM; ++i) s += base[(size_t)i * HIDDEN];
    out[(size_t)mol * HIDDEN + h] = s * (1.0f / APM);
}

extern "C" void kernel_launch(void* const* d_in, const int* in_sizes, int n_in,
                              void* d_out, int out_size, void* d_ws, size_t ws_size,
                              hipStream_t stream)
{
    const float* f_atoms = (const float*)d_in[0];
    const float* f_bonds = (const float*)d_in[1];
    const int* a2b    = (const int*)d_in[2];
    const int* b2a    = (const int*)d_in[3];
    const int* b2revb = (const int*)d_in[4];
    const float* W_i  = (const float*)d_in[6];
    const float* W_h  = (const float*)d_in[7];
    const float* W_o  = (const float*)d_in[8];
    const float* b_o  = (const float*)d_in[9];
    float* out = (float*)d_out;

    char* ws = (char*)d_ws;
    size_t off = 0;
    auto alloc = [&](size_t n) { char* p = ws + off; off = (off + n + 255) & ~(size_t)255; return p; };
    unsigned short* wi   = (unsigned short*)alloc((size_t)256 * KI * 2);
    unsigned short* wh   = (unsigned short*)alloc((size_t)256 * 256 * 2);
    unsigned short* wo   = (unsigned short*)alloc((size_t)256 * KO * 2);
    unsigned short* inp  = (unsigned short*)alloc((size_t)B1 * HIDDEN * 2);
    unsigned short* msgA = (unsigned short*)alloc((size_t)B1 * HIDDEN * 2);
    unsigned short* msgB = (unsigned short*)alloc((size_t)B1 * HIDDEN * 2);
    unsigned short* amsg = (unsigned short*)alloc((size_t)A1 * HIDDEN * 2);
    float* ah = (float*)inp;  // overlay: inp is dead after the last k_gemm_wh

    k_convw<<<832, 256, 0, stream>>>(W_i, W_h, W_o, wi, wh, wo);

    const int gb = (B1 + 63) / 64;            // 5001
    const int ga = (A1 + 63) / 64;            // 2344
    const int gg = (A1 * 32 + 255) / 256;     // 18751

    k_gemm_wi<<<gb, 256, 0, stream>>>(f_bonds, wi, inp, msgA);

    unsigned short* cur = msgA;
    unsigned short* nxt = msgB;
    for (int it = 0; it < 5; ++it) {
        k_gather<<<gg, 256, 0, stream>>>(cur, a2b, amsg);
        k_gemm_wh<<<gb, 256, 0, stream>>>(amsg, cur, b2a, b2revb, wh, inp, nxt);
        unsigned short* t = cur; cur = nxt; nxt = t;
    }
    k_gather<<<gg, 256, 0, stream>>>(cur, a2b, amsg);
    k_gemm_wo<<<ga, 256, 0, stream>>>(f_atoms, amsg, wo, b_o, ah);
    k_pool<<<NMOLS, 256, 0, stream>>>(ah, out);
}

// Round 2
// 1674.361 us; speedup vs baseline: 1.0898x; 1.0898x over previous
//
#include <hip/hip_runtime.h>
#include <stdint.h>

#define HIDDEN 256
#define NMOLS 5000
#define APM 30
#define NATOMS 150000
#define NBONDS 320000
#define MAXNB 6
#define AFD 133
#define BFD 147
#define A1 (NATOMS + 1)
#define B1 (NBONDS + 1)
#define KI 160    // MFMA K extent for W_i GEMM (147 -> 160)
#define KIP 168   // LDS row padding for A-tile (336 B rows: 2-way bank aliasing only)
#define KO 416    // padded readout K (133 f_atoms + 27 pad + 256 amsg)

typedef __bf16 bfx8 __attribute__((ext_vector_type(8)));
typedef float fx4 __attribute__((ext_vector_type(4)));
typedef unsigned short u16x8 __attribute__((ext_vector_type(8)));

__device__ __forceinline__ float b2f(unsigned short u) {
    union { unsigned int i; float f; } v; v.i = ((unsigned int)u) << 16; return v.f;
}
__device__ __forceinline__ unsigned short f2b(float f) {
    union { float f; unsigned int i; } v; v.f = f;
    unsigned int r = v.i + 0x7FFFu + ((v.i >> 16) & 1u);
    return (unsigned short)(r >> 16);
}

// ---------------- weight conversion / padding ----------------
__global__ void k_convw(const float* __restrict__ Wi, const float* __restrict__ Wh,
                        const float* __restrict__ Wo,
                        unsigned short* __restrict__ wi, unsigned short* __restrict__ wh,
                        unsigned short* __restrict__ wo) {
    int t = blockIdx.x * 256 + threadIdx.x;
    if (t < 256 * KI) {
        int n = t / KI, k = t % KI;
        wi[t] = (k < BFD) ? f2b(Wi[n * BFD + k]) : (unsigned short)0;
        return;
    }
    int t2 = t - 256 * KI;
    if (t2 < 256 * 256) {
        wh[t2] = f2b(Wh[t2]);
        return;
    }
    int t3 = t2 - 256 * 256;
    if (t3 < 256 * KO) {
        int n = t3 / KO, k = t3 % KO;
        float v = 0.f;
        if (k < AFD) v = Wo[n * (AFD + HIDDEN) + k];
        else if (k >= 160) v = Wo[n * (AFD + HIDDEN) + AFD + (k - 160)];
        wo[t3] = f2b(v);
    }
}

// ---------------- K1: inp = f_bonds @ Wi^T (bf16 out, no msg write) ----------------
__global__ __launch_bounds__(256) void k_gemm_wi(
    const float* __restrict__ fb, const unsigned short* __restrict__ wi,
    unsigned short* __restrict__ inp)
{
    __shared__ float s_f32[64 * BFD];          // 37632 B, flat copy of 64 rows
    __shared__ unsigned short s_bf[64 * KIP];  // 21504 B, padded bf16 A-tile
    const int m0 = blockIdx.x * 64;
    const int tid = threadIdx.x;

    // stage 1: coalesced float4 flat copy (region start is 16B-aligned: 64*588 = 37632)
    {
        const size_t base = (size_t)m0 * BFD;
        const size_t tot = (size_t)B1 * BFD;
        const float4* src4 = (const float4*)(fb + base);
#pragma unroll
        for (int i = 0; i < 10; ++i) {
            const int t4 = i * 256 + tid;
            if (t4 < (64 * BFD) / 4) {
                const size_t f = base + (size_t)t4 * 4;
                float4 v;
                if (f + 4 <= tot) {
                    v = src4[t4];
                } else {
                    v.x = (f + 0 < tot) ? fb[f + 0] : 0.f;
                    v.y = (f + 1 < tot) ? fb[f + 1] : 0.f;
                    v.z = (f + 2 < tot) ? fb[f + 2] : 0.f;
                    v.w = (f + 3 < tot) ? fb[f + 3] : 0.f;
                }
                *(float4*)(s_f32 + t4 * 4) = v;
            }
        }
    }
    __syncthreads();

    // stage 2: LDS f32 -> LDS bf16 padded tile
    {
        const int r = tid >> 2, p = tid & 3;
        const float* srow = s_f32 + r * BFD;
        unsigned short* drow = s_bf + r * KIP;
#pragma unroll
        for (int i = 0; i < 5; ++i) {
            const int c0 = (i * 4 + p) * 8;   // 0..152
            u16x8 o;
#pragma unroll
            for (int e = 0; e < 8; ++e) {
                float v = (c0 + e < BFD) ? srow[c0 + e] : 0.f;
                o[e] = f2b(v);
            }
            *(u16x8*)(drow + c0) = o;
        }
    }
    __syncthreads();

    const int wv = tid >> 6, ln = tid & 63;
    const int l15 = ln & 15, lhi = ln >> 4;
    fx4 acc[4][4];
#pragma unroll
    for (int a = 0; a < 4; ++a)
#pragma unroll
        for (int b = 0; b < 4; ++b)
#pragma unroll
            for (int q = 0; q < 4; ++q) acc[a][b][q] = 0.f;

#pragma unroll
    for (int ks = 0; ks < 5; ++ks) {
        const int kk = ks * 32 + lhi * 8;
        bfx8 af[4], bb[4];
#pragma unroll
        for (int mf = 0; mf < 4; ++mf) {
            const int rr = mf * 16 + l15;
            af[mf] = *(const bfx8*)(s_bf + rr * KIP + kk);
        }
#pragma unroll
        for (int nf = 0; nf < 4; ++nf) {
            const int n = wv * 64 + nf * 16 + l15;
            bb[nf] = *(const bfx8*)(wi + n * KI + kk);
        }
#pragma unroll
        for (int mf = 0; mf < 4; ++mf)
#pragma unroll
            for (int nf = 0; nf < 4; ++nf)
                acc[mf][nf] = __builtin_amdgcn_mfma_f32_16x16x32_bf16(af[mf], bb[nf], acc[mf][nf], 0, 0, 0);
    }
    const int cb = wv * 64 + l15;
    const int rb = lhi * 4;
#pragma unroll
    for (int mf = 0; mf < 4; ++mf) {
#pragma unroll
        for (int j = 0; j < 4; ++j) {
            const int g = m0 + mf * 16 + rb + j;
            if (g < B1) {
#pragma unroll
                for (int nf = 0; nf < 4; ++nf) {
                    inp[(size_t)g * HIDDEN + cb + nf * 16] = f2b(acc[mf][nf][j]);
                }
            }
        }
    }
}

// ---------------- K2: amsg[a] = sum_j msg[a2b[a][j]]  (optionally relu on read) ----------------
__global__ __launch_bounds__(256) void k_gather(
    const unsigned short* __restrict__ msg, const int* __restrict__ a2b,
    unsigned short* __restrict__ amsg, const int relu_src)
{
    const int gt = blockIdx.x * 256 + threadIdx.x;
    const int atom = gt >> 5;
    const int s = gt & 31;
    if (atom >= A1) return;
    const int* nb = a2b + atom * MAXNB;
    float acc[8];
#pragma unroll
    for (int e = 0; e < 8; ++e) acc[e] = 0.f;
#pragma unroll
    for (int j = 0; j < MAXNB; ++j) {
        const int b = nb[j];
        u16x8 v = *(const u16x8*)(msg + (size_t)b * HIDDEN + s * 8);
#pragma unroll
        for (int e = 0; e < 8; ++e) {
            float x = b2f(v[e]);
            if (relu_src) x = x > 0.f ? x : 0.f;
            acc[e] += x;
        }
    }
    u16x8 o;
#pragma unroll
    for (int e = 0; e < 8; ++e) o[e] = f2b(acc[e]);
    *(u16x8*)(amsg + (size_t)atom * HIDDEN + s * 8) = o;
}

// ---------------- K3: msgn = relu(inp + (amsg[b2a]-msgp[b2revb]) @ Wh^T) ----------------
__global__ __launch_bounds__(256) void k_gemm_wh(
    const unsigned short* __restrict__ amsg,
    const unsigned short* __restrict__ msgp,
    const int* __restrict__ b2a, const int* __restrict__ b2revb,
    const unsigned short* __restrict__ wh,
    const unsigned short* __restrict__ inp,
    unsigned short* __restrict__ msgn, const int relu_rev)
{
    __shared__ unsigned short lds[64 * 256];  // 512 B rows, XOR-swizzled
    const int m0 = blockIdx.x * 64;
    const int tid = threadIdx.x;
    {
        const int r = tid >> 2, p = tid & 3;
        const int b = m0 + r;
        const bool ok = (b < B1);
        int i1 = 0, i2 = 0;
        if (ok) { i1 = b2a[b]; i2 = b2revb[b]; }
        const unsigned short* s1 = amsg + (size_t)i1 * HIDDEN;
        const unsigned short* s2 = msgp + (size_t)i2 * HIDDEN;
        char* ldsrow = (char*)lds + r * 512;
        const int sw = (r & 7) << 4;
#pragma unroll
        for (int i = 0; i < 8; ++i) {
            const int slot = i * 4 + p;
            const int c0 = slot * 8;
            u16x8 o;
            if (ok) {
                u16x8 a = *(const u16x8*)(s1 + c0);
                u16x8 m = *(const u16x8*)(s2 + c0);
#pragma unroll
                for (int e = 0; e < 8; ++e) {
                    float mv = b2f(m[e]);
                    if (relu_rev) mv = mv > 0.f ? mv : 0.f;
                    o[e] = f2b(b2f(a[e]) - mv);
                }
            } else {
#pragma unroll
                for (int e = 0; e < 8; ++e) o[e] = 0;
            }
            *(u16x8*)(ldsrow + ((slot * 16) ^ sw)) = o;
        }
    }
    __syncthreads();

    const int wv = tid >> 6, ln = tid & 63;
    const int l15 = ln & 15, lhi = ln >> 4;
    fx4 acc[4][4];
#pragma unroll
    for (int a = 0; a < 4; ++a)
#pragma unroll
        for (int b = 0; b < 4; ++b)
#pragma unroll
            for (int q = 0; q < 4; ++q) acc[a][b][q] = 0.f;

#pragma unroll
    for (int ks = 0; ks < 8; ++ks) {
        const int kk = ks * 32 + lhi * 8;
        bfx8 af[4], bb[4];
#pragma unroll
        for (int mf = 0; mf < 4; ++mf) {
            const int rr = mf * 16 + l15;
            af[mf] = *(const bfx8*)((const char*)lds + rr * 512 + ((kk * 2) ^ ((rr & 7) << 4)));
        }
#pragma unroll
        for (int nf = 0; nf < 4; ++nf) {
            const int n = wv * 64 + nf * 16 + l15;
            bb[nf] = *(const bfx8*)(wh + n * 256 + kk);
        }
#pragma unroll
        for (int mf = 0; mf < 4; ++mf)
#pragma unroll
            for (int nf = 0; nf < 4; ++nf)
                acc[mf][nf] = __builtin_amdgcn_mfma_f32_16x16x32_bf16(af[mf], bb[nf], acc[mf][nf], 0, 0, 0);
    }
    const int cb = wv * 64 + l15;
    const int rb = lhi * 4;
#pragma unroll
    for (int mf = 0; mf < 4; ++mf) {
#pragma unroll
        for (int j = 0; j < 4; ++j) {
            const int g = m0 + mf * 16 + rb + j;
            if (g < B1) {
#pragma unroll
                for (int nf = 0; nf < 4; ++nf) {
                    const size_t idx = (size_t)g * HIDDEN + cb + nf * 16;
                    float v = b2f(inp[idx]) + acc[mf][nf][j];
                    msgn[idx] = f2b(v > 0.f ? v : 0.f);
                }
            }
        }
    }
}

// ---------------- K4: atom_hiddens(bf16) = relu(concat(f_atoms, amsg) @ Wo^T + bo) ----------------
__global__ __launch_bounds__(256) void k_gemm_wo(
    const float* __restrict__ fa,
    const unsigned short* __restrict__ amsg,
    const unsigned short* __restrict__ wo,
    const float* __restrict__ bo,
    unsigned short* __restrict__ ah)
{
    __shared__ unsigned short lds[64 * KO];  // 53248 B, 832 B rows (2-way aliasing)
    const int m0 = blockIdx.x * 64;
    const int tid = threadIdx.x;
    {
        const int r = tid >> 2, p = tid & 3;
        const int a = m0 + r;
        const bool ok = (a < A1);
        const float* src = fa + (size_t)a * AFD;
        unsigned short* drow = lds + r * KO;
#pragma unroll
        for (int i = 0; i < 13; ++i) {
            const int c0 = (i * 4 + p) * 8;
            u16x8 o;
            if (ok && c0 + 8 <= AFD) {
#pragma unroll
                for (int e = 0; e < 8; ++e) o[e] = f2b(src[c0 + e]);
            } else if (ok && c0 < AFD) {
#pragma unroll
                for (int e = 0; e < 8; ++e) o[e] = (c0 + e < AFD) ? f2b(src[c0 + e]) : (unsigned short)0;
            } else if (ok && c0 >= 160) {
                o = *(const u16x8*)(amsg + (size_t)a * HIDDEN + (c0 - 160));
            } else {
#pragma unroll
                for (int e = 0; e < 8; ++e) o[e] = 0;
            }
            *(u16x8*)(drow + c0) = o;
        }
    }
    __syncthreads();

    const int wv = tid >> 6, ln = tid & 63;
    const int l15 = ln & 15, lhi = ln >> 4;
    fx4 acc[4][4];
#pragma unroll
    for (int a = 0; a < 4; ++a)
#pragma unroll
        for (int b = 0; b < 4; ++b)
#pragma unroll
            for (int q = 0; q < 4; ++q) acc[a][b][q] = 0.f;

#pragma unroll
    for (int ks = 0; ks < 13; ++ks) {
        const int kk = ks * 32 + lhi * 8;
        bfx8 af[4], bb[4];
#pragma unroll
        for (int mf = 0; mf < 4; ++mf) {
            const int rr = mf * 16 + l15;
            af[mf] = *(const bfx8*)(lds + rr * KO + kk);
        }
#pragma unroll
        for (int nf = 0; nf < 4; ++nf) {
            const int n = wv * 64 + nf * 16 + l15;
            bb[nf] = *(const bfx8*)(wo + n * KO + kk);
        }
#pragma unroll
        for (int mf = 0; mf < 4; ++mf)
#pragma unroll
            for (int nf = 0; nf < 4; ++nf)
                acc[mf][nf] = __builtin_amdgcn_mfma_f32_16x16x32_bf16(af[mf], bb[nf], acc[mf][nf], 0, 0, 0);
    }
    const int cb = wv * 64 + l15;
    const int rb = lhi * 4;
    float bias[4];
#pragma unroll
    for (int nf = 0; nf < 4; ++nf) bias[nf] = bo[cb + nf * 16];
#pragma unroll
    for (int mf = 0; mf < 4; ++mf) {
#pragma unroll
        for (int j = 0; j < 4; ++j) {
            const int g = m0 + mf * 16 + rb + j;
            if (g < A1) {
#pragma unroll
                for (int nf = 0; nf < 4; ++nf) {
                    float v = acc[mf][nf][j] + bias[nf];
                    ah[(size_t)g * HIDDEN + cb + nf * 16] = f2b(v > 0.f ? v : 0.f);
                }
            }
        }
    }
}

// ---------------- K5: per-molecule mean over 30 atoms (bf16 in, f32 out) ----------------
__global__ __launch_bounds__(256) void k_pool(const unsigned short* __restrict__ ah,
                                              float* __restrict__ out) {
    const int mol = blockIdx.x;
    const int h = threadIdx.x;
    const unsigned short* base = ah + ((size_t)(1 + mol * APM)) * HIDDEN + h;
    float s = 0.f;
#pragma unroll
    for (int i = 0; i < APM; ++i) s += b2f(base[(size_t)i * HIDDEN]);
    out[(size_t)mol * HIDDEN + h] = s * (1.0f / APM);
}

extern "C" void kernel_launch(void* const* d_in, const int* in_sizes, int n_in,
                              void* d_out, int out_size, void* d_ws, size_t ws_size,
                              hipStream_t stream)
{
    const float* f_atoms = (const float*)d_in[0];
    const float* f_bonds = (const float*)d_in[1];
    const int* a2b    = (const int*)d_in[2];
    const int* b2a    = (const int*)d_in[3];
    const int* b2revb = (const int*)d_in[4];
    const float* W_i  = (const float*)d_in[6];
    const float* W_h  = (const float*)d_in[7];
    const float* W_o  = (const float*)d_in[8];
    const float* b_o  = (const float*)d_in[9];
    float* out = (float*)d_out;

    char* ws = (char*)d_ws;
    size_t off = 0;
    auto alloc = [&](size_t n) { char* p = ws + off; off = (off + n + 255) & ~(size_t)255; return p; };
    unsigned short* wi   = (unsigned short*)alloc((size_t)256 * KI * 2);
    unsigned short* wh   = (unsigned short*)alloc((size_t)256 * 256 * 2);
    unsigned short* wo   = (unsigned short*)alloc((size_t)256 * KO * 2);
    unsigned short* inp  = (unsigned short*)alloc((size_t)B1 * HIDDEN * 2);
    unsigned short* msgA = (unsigned short*)alloc((size_t)B1 * HIDDEN * 2);
    unsigned short* msgB = (unsigned short*)alloc((size_t)B1 * HIDDEN * 2);
    unsigned short* amsg = (unsigned short*)alloc((size_t)A1 * HIDDEN * 2);
    unsigned short* ah = inp;  // overlay: inp is dead after the last k_gemm_wh

    k_convw<<<832, 256, 0, stream>>>(W_i, W_h, W_o, wi, wh, wo);

    const int gb = (B1 + 63) / 64;            // 5001
    const int ga = (A1 + 63) / 64;            // 2344
    const int gg = (A1 * 32 + 255) / 256;     // 18751

    k_gemm_wi<<<gb, 256, 0, stream>>>(f_bonds, wi, inp);

    // iteration 0: message source is relu(inp), applied on read
    k_gather<<<gg, 256, 0, stream>>>(inp, a2b, amsg, 1);
    k_gemm_wh<<<gb, 256, 0, stream>>>(amsg, inp, b2a, b2revb, wh, inp, msgA, 1);

    unsigned short* cur = msgA;
    unsigned short* nxt = msgB;
    for (int it = 1; it < 5; ++it) {
        k_gather<<<gg, 256, 0, stream>>>(cur, a2b, amsg, 0);
        k_gemm_wh<<<gb, 256, 0, stream>>>(amsg, cur, b2a, b2revb, wh, inp, nxt, 0);
        unsigned short* t = cur; cur = nxt; nxt = t;
    }
    k_gather<<<gg, 256, 0, stream>>>(cur, a2b, amsg, 0);
    k_gemm_wo<<<ga, 256, 0, stream>>>(f_atoms, amsg, wo, b_o, ah);
    k_pool<<<NMOLS, 256, 0, stream>>>(ah, out);
}